// Round 8
// baseline (269.702 us; speedup 1.0000x reference)
//
#include <hip/hip_runtime.h>
#include <hip/hip_fp16.h>

// GAT (2 layers, heads=1) + 2-layer MLP head. N=100000, E=3200000, D=128.
// R23 = R22 + csplit LDS diet: the 8KB rid[] array is folded into lsrt's
// free top byte (pair payload is 24 bits). Flush recovers the bucket id
// branchlessly: largest candidate c in {b, b+256, b+512, b+768} with
// lofs[c] <= i (runs are bucket-ordered -> lofs monotone over candidates).
// csplit LDS 36.9KB -> 28.7KB -> 5 blocks/CU (was 4). Flush fully unrolled.
// agg1 sort + sorted write-back, agg2 sort-free (R22, proven).
// Overflow -> full-rescan fallback keeps arbitrary inputs correct.
// Softmax stabilization uses a GLOBAL upper bound m̄_i = leaky(gmax_asrc+adst_i)
// (valid since leaky_relu is monotone); alpha is mathematically unchanged.

#define NEG 0.2f
#define FSH 7
#define BNODES 128           // nodes per bucket
#define NSBMAX 1024          // >= ceil(100000/128)=782
#define CAPB 4608            // per-bucket region capacity (mean 4096, +8 sigma)
#define TILE 4096            // edges per csplit block (256 threads, 16/thread)
#define EPT 16               // TILE/256 register-staged edges per thread
#define PES 9                // ceil(CAPB/512) register-staged pairs per thread
#define LOFSTR 132           // lofs_g stride per bucket (129 lofs + flag + pad)

__device__ __forceinline__ float lrelu(float x) { return x > 0.0f ? x : NEG * x; }

__device__ __forceinline__ unsigned fenc(float f) {
    unsigned u = __float_as_uint(f);
    return (u & 0x80000000u) ? ~u : (u | 0x80000000u);
}
__device__ __forceinline__ float fdec(unsigned e) {
    return (e & 0x80000000u) ? __uint_as_float(e & 0x7FFFFFFFu) : __uint_as_float(~e);
}

// load 4 consecutive halves as float4 (8B load)
__device__ __forceinline__ float4 ldh4(const __half* h, size_t off) {
    uint2 u = *(const uint2*)(h + off);
    __half2 a = *(__half2*)&u.x, b = *(__half2*)&u.y;
    float2 fa = __half22float2(a), fb = __half22float2(b);
    return make_float4(fa.x, fa.y, fb.x, fb.y);
}

// ---- fused front-end: gemm role + csplit role in one grid ----
__global__ __launch_bounds__(256) void k_front(
    const float* __restrict__ x, const float* __restrict__ W1,
    const float* __restrict__ a1s, const float* __restrict__ a1d,
    __half* __restrict__ h1, float* __restrict__ s1, float* __restrict__ d1,
    unsigned* __restrict__ gmax,
    const int* __restrict__ esrc, const int* __restrict__ edst,
    int* __restrict__ bcur, unsigned* __restrict__ pairs,
    int N, int E, int NG, int NC, int NSB)
{
    // union LDS: csplit lsrt 4096 + hist/ofs/base 3*1024 + wsum 4 = 7172 words
    //            (28.7KB -> 5 blocks/CU); gemm: padded W 2060 + wm 4 (8.3KB)
    __shared__ float smem[7172];
    int tid = threadIdx.x;
    int bid = blockIdx.x;
    long long T = (long long)NG + NC;
    int before = (int)(((long long)bid * NC) / T);
    int isc = (int)((((long long)bid + 1) * NC) / T) > before;

    if (isc) {
        // ------------------ csplit role ------------------
        unsigned* lsrt = (unsigned*)smem;                   // TILE
        int* lhist = (int*)smem + TILE;                     // 1024
        int* lofs  = lhist + NSBMAX;                        // 1024
        int* gbase = lofs + NSBMAX;                         // 1024
        int* wsum  = gbase + NSBMAX;                        // 4
        int cid = before;
        int base = cid * TILE;
        int tcnt = min(TILE, E - base);
        for (int i = tid; i < NSB; i += 256) lhist[i] = 0;
        __syncthreads();
        // hist pass with register-staged dst
        int ed[EPT];
#pragma unroll
        for (int u = 0; u < EPT; ++u) {
            int i = tid + u * 256;
            ed[u] = (i < tcnt) ? edst[base + i] : -1;
            if (ed[u] >= 0) atomicAdd(&lhist[ed[u] >> FSH], 1);
        }
        __syncthreads();
        // 4 keys per thread scan (NSB <= 1024 = 4*256)
        int i0 = 4 * tid;
        int a0 = (i0 + 0 < NSB) ? lhist[i0 + 0] : 0;
        int a1 = (i0 + 1 < NSB) ? lhist[i0 + 1] : 0;
        int a2 = (i0 + 2 < NSB) ? lhist[i0 + 2] : 0;
        int a3 = (i0 + 3 < NSB) ? lhist[i0 + 3] : 0;
        int s = a0 + a1 + a2 + a3, pfx = s;
#pragma unroll
        for (int off = 1; off < 64; off <<= 1) {
            int t = __shfl_up(pfx, off, 64);
            if ((tid & 63) >= off) pfx += t;
        }
        if ((tid & 63) == 63) wsum[tid >> 6] = pfx;
        __syncthreads();
        int carry = 0;
        for (int w = 0; w < (tid >> 6); ++w) carry += wsum[w];
        int excl = pfx + carry - s;
        if (i0 + 0 < NSB) { lofs[i0 + 0] = excl;                 gbase[i0 + 0] = a0 ? atomicAdd(&bcur[(i0 + 0) * 16], a0) : 0; }
        if (i0 + 1 < NSB) { lofs[i0 + 1] = excl + a0;            gbase[i0 + 1] = a1 ? atomicAdd(&bcur[(i0 + 1) * 16], a1) : 0; }
        if (i0 + 2 < NSB) { lofs[i0 + 2] = excl + a0 + a1;       gbase[i0 + 2] = a2 ? atomicAdd(&bcur[(i0 + 2) * 16], a2) : 0; }
        if (i0 + 3 < NSB) { lofs[i0 + 3] = excl + a0 + a1 + a2;  gbase[i0 + 3] = a3 ? atomicAdd(&bcur[(i0 + 3) * 16], a3) : 0; }
        __syncthreads();
        if (i0 + 0 < NSB) lhist[i0 + 0] = lofs[i0 + 0];   // cursors
        if (i0 + 1 < NSB) lhist[i0 + 1] = lofs[i0 + 1];
        if (i0 + 2 < NSB) lhist[i0 + 2] = lofs[i0 + 2];
        if (i0 + 3 < NSB) lhist[i0 + 3] = lofs[i0 + 3];
        __syncthreads();
        // scatter: sorted position + bucket-low-8 packed into lsrt top byte
#pragma unroll
        for (int u = 0; u < EPT; ++u) {
            int i = tid + u * 256;
            if (ed[u] >= 0) {
                int d = ed[u], srcv = esrc[base + i];
                int b = d >> FSH;
                int pos = atomicAdd(&lhist[b], 1);
                lsrt[pos] = ((unsigned)(b & 255) << 24)
                          | ((unsigned)(d & (BNODES - 1)) << 17) | (unsigned)srcv;
            }
        }
        __syncthreads();
        // flush: recover bucket id = largest candidate with lofs[c] <= i
        // (runs are bucket-ordered -> lofs monotone over candidates)
#pragma unroll
        for (int u = 0; u < EPT; ++u) {
            int i = tid + u * 256;
            if (i < tcnt) {
                unsigned v = lsrt[i];
                int c = (int)(v >> 24);
                int c2 = c + 256; if (c2 < NSB && lofs[c2] <= i) c = c2;
                int c3 = c + 256; if (c3 < NSB && lofs[c3] <= i) c = c3;
                int c4 = c + 256; if (c4 < NSB && lofs[c4] <= i) c = c4;
                int rel = gbase[c] + (i - lofs[c]);
                if (rel < CAPB) pairs[(size_t)c * CAPB + rel] = v & 0x00FFFFFFu;
            }
        }
        return;
    }

    // gemm role (no x stage; j-partitioned lanes)
    float* sW = smem;
    float* wm = smem + 2060;
    int gid = bid - before;
    for (int i = tid; i < 2048; i += 256) sW[i + ((i >> 9) << 2)] = W1[i];
    int node0 = gid * 64;
    int node = node0 + (tid >> 2);
    int q = tid & 3;
    bool valid = node < N;
    float4 xr[8];
    {
        const float4* xp = (const float4*)x + (size_t)node * 32 + q * 8;
#pragma unroll
        for (int k = 0; k < 8; ++k)
            xr[k] = valid ? xp[k] : make_float4(0.f, 0.f, 0.f, 0.f);
    }
    __syncthreads();

    float acc[16];
#pragma unroll
    for (int c = 0; c < 16; ++c) acc[c] = 0.f;
    int wbase = q * 516;
#pragma unroll
    for (int k = 0; k < 8; ++k) {
        float xs0 = xr[k].x, xs1 = xr[k].y, xs2 = xr[k].z, xs3 = xr[k].w;
#pragma unroll
        for (int t = 0; t < 4; ++t) {
            float xv = (t == 0) ? xs0 : (t == 1) ? xs1 : (t == 2) ? xs2 : xs3;
            const float4* wrow = (const float4*)&sW[wbase + (k * 4 + t) * 16];
            float4 w0 = wrow[0], w1 = wrow[1], w2 = wrow[2], w3 = wrow[3];
            acc[0]  += xv * w0.x; acc[1]  += xv * w0.y; acc[2]  += xv * w0.z; acc[3]  += xv * w0.w;
            acc[4]  += xv * w1.x; acc[5]  += xv * w1.y; acc[6]  += xv * w1.z; acc[7]  += xv * w1.w;
            acc[8]  += xv * w2.x; acc[9]  += xv * w2.y; acc[10] += xv * w2.z; acc[11] += xv * w2.w;
            acc[12] += xv * w3.x; acc[13] += xv * w3.y; acc[14] += xv * w3.z; acc[15] += xv * w3.w;
        }
    }
#pragma unroll
    for (int c = 0; c < 16; ++c) {
        acc[c] += __shfl_xor(acc[c], 1);
        acc[c] += __shfl_xor(acc[c], 2);
    }
    float sv = 0.f, dv = 0.f;
    {
        const float4* asp = (const float4*)a1s;
        const float4* adp = (const float4*)a1d;
#pragma unroll
        for (int r = 0; r < 4; ++r) {
            float4 as = asp[r], ad = adp[r];
            sv += acc[r*4+0]*as.x + acc[r*4+1]*as.y + acc[r*4+2]*as.z + acc[r*4+3]*as.w;
            dv += acc[r*4+0]*ad.x + acc[r*4+1]*ad.y + acc[r*4+2]*ad.z + acc[r*4+3]*ad.w;
        }
    }
    if (valid) {
        float4 av;
        if      (q == 0) av = make_float4(acc[0],  acc[1],  acc[2],  acc[3]);
        else if (q == 1) av = make_float4(acc[4],  acc[5],  acc[6],  acc[7]);
        else if (q == 2) av = make_float4(acc[8],  acc[9],  acc[10], acc[11]);
        else             av = make_float4(acc[12], acc[13], acc[14], acc[15]);
        __half2 p0 = __floats2half2_rn(av.x, av.y);
        __half2 p1 = __floats2half2_rn(av.z, av.w);
        uint2 u; u.x = *(unsigned*)&p0; u.y = *(unsigned*)&p1;
        *(uint2*)&h1[(size_t)node * 16 + q * 4] = u;
        if (q == 0) { s1[node] = sv; d1[node] = dv; }
    }
    float m = valid ? sv : -3.4e38f;
#pragma unroll
    for (int off = 32; off >= 1; off >>= 1) m = fmaxf(m, __shfl_xor(m, off));
    if ((tid & 63) == 0) wm[tid >> 6] = m;
    __syncthreads();
    if (tid == 0) {
        float b = fmaxf(fmaxf(wm[0], wm[1]), fmaxf(wm[2], wm[3]));
        atomicMax(gmax, fenc(b));
    }
}

// ---- layer-1 agg: R11 full-bucket sort+gather, plus sorted write-back ----
__global__ __launch_bounds__(512) void k_agg1(
    const int* __restrict__ bcur, unsigned* __restrict__ pairs,
    const int* __restrict__ esrc, const int* __restrict__ edst,
    const float* __restrict__ s1, const float* __restrict__ d1, const __half* __restrict__ h1,
    const float* __restrict__ b1, const float* __restrict__ W2,
    const float* __restrict__ a2s, const float* __restrict__ a2d,
    __half* __restrict__ h2, float* __restrict__ s2, float* __restrict__ d2,
    const unsigned* __restrict__ gmax1p, unsigned* __restrict__ gmax2,
    int* __restrict__ lofs_g, int N, int E)
{
    __shared__ unsigned srt[CAPB];
    __shared__ float accs[BNODES * 17];
    __shared__ int lcnt[BNODES];
    __shared__ int lofs[BNODES + 1];
    __shared__ float dds[BNODES], mbs[BNODES];
    __shared__ float sW[160], sb[16], sas[16], sad[16];
    __shared__ int wsum[8];
    __shared__ float wm[8];

    int tid = threadIdx.x;
    int fb = blockIdx.x;
    if (tid < 160) sW[tid] = W2[tid];
    if (tid < 16) {
        sb[tid]  = b1[tid];
        sas[tid] = (tid < 10) ? a2s[tid] : 0.f;
        sad[tid] = (tid < 10) ? a2d[tid] : 0.f;
    }
    int node0 = fb << FSH;
    float g0 = fdec(*gmax1p);
    if (tid < BNODES) {
        int n = node0 + tid;
        float dd = (n < N) ? d1[n] : 0.f;
        dds[tid] = dd; mbs[tid] = lrelu(g0 + dd);
        lcnt[tid] = 0;
    }
    __syncthreads();

    int rbase = fb * CAPB;
    int cnt = bcur[fb * 16];             // RELATIVE count; > CAPB means overflow
    int gg = tid >> 2, q = tid & 3;      // 128 groups x 4 lanes, 1 node each

    if (cnt <= CAPB) {
        // count pass with register staging (single global read of pairs)
        unsigned pe[PES];
#pragma unroll
        for (int u = 0; u < PES; ++u) {
            int i = tid + u * 512;
            bool ok = (i < cnt);
            pe[u] = ok ? pairs[rbase + i] : 0u;
            if (ok) atomicAdd(&lcnt[(pe[u] >> 17) & (BNODES - 1)], 1);
        }
        __syncthreads();
        // 128-key scan (padded to 512 threads)
        int c = (tid < BNODES) ? lcnt[tid] : 0;
        int pfx = c;
#pragma unroll
        for (int off = 1; off < 64; off <<= 1) {
            int t = __shfl_up(pfx, off, 64);
            if ((tid & 63) >= off) pfx += t;
        }
        if ((tid & 63) == 63) wsum[tid >> 6] = pfx;
        __syncthreads();
        int carry = 0;
        for (int w = 0; w < (tid >> 6); ++w) carry += wsum[w];
        pfx += carry;
        if (tid < BNODES) { lofs[tid + 1] = pfx; lcnt[tid] = pfx - c; }
        if (tid == 0) lofs[0] = 0;
        __syncthreads();
        // scatter pass from registers -> dst-sorted srcs
#pragma unroll
        for (int u = 0; u < PES; ++u) {
            int i = tid + u * 512;
            if (i < cnt) {
                unsigned p = pe[u];
                int pos = atomicAdd(&lcnt[(p >> 17) & (BNODES - 1)], 1);
                srt[pos] = p & 0x1FFFF;
            }
        }
        __syncthreads();

        // write-back sorted srcs over own region + lofs for the sort-free agg2
#pragma unroll
        for (int u = 0; u < PES; ++u) {
            int i = tid + u * 512;
            if (i < cnt) pairs[rbase + i] = srt[i];
        }
        if (tid <= BNODES) lofs_g[fb * LOFSTR + tid] = lofs[tid];
        if (tid == 0) lofs_g[fb * LOFSTR + BNODES + 1] = 1;

        // self-loop init + register gather (1 exp/edge via width-4 shfl)
        int n = node0 + gg;
        float4 accv; float den;
        if (n < N) {
            float w = __expf(lrelu(s1[n] + dds[gg]) - mbs[gg]);
            float4 hv = ldh4(h1, (size_t)n * 16 + 4 * q);
            accv = make_float4(w * hv.x, w * hv.y, w * hv.z, w * hv.w);
            den = w;
        } else { accv = make_float4(0.f, 0.f, 0.f, 0.f); den = 0.f; }
        {
            float dd = dds[gg], mb = mbs[gg];
            int j = lofs[gg], j1 = lofs[gg + 1];
            for (; j + 4 <= j1; j += 4) {
                int e0 = srt[j], e1 = srt[j + 1], e2 = srt[j + 2], e3 = srt[j + 3];
                float4 H0 = ldh4(h1, (size_t)e0 * 16 + 4 * q);
                float4 H1 = ldh4(h1, (size_t)e1 * 16 + 4 * q);
                float4 H2 = ldh4(h1, (size_t)e2 * 16 + 4 * q);
                float4 H3 = ldh4(h1, (size_t)e3 * 16 + 4 * q);
                int eq = srt[j + q];
                float wq = __expf(lrelu(s1[eq] + dd) - mb);
                float w0 = __shfl(wq, 0, 4), w1 = __shfl(wq, 1, 4);
                float w2 = __shfl(wq, 2, 4), w3 = __shfl(wq, 3, 4);
                accv.x += w0 * H0.x + w1 * H1.x + w2 * H2.x + w3 * H3.x;
                accv.y += w0 * H0.y + w1 * H1.y + w2 * H2.y + w3 * H3.y;
                accv.z += w0 * H0.z + w1 * H1.z + w2 * H2.z + w3 * H3.z;
                accv.w += w0 * H0.w + w1 * H1.w + w2 * H2.w + w3 * H3.w;
                den += (w0 + w1) + (w2 + w3);
            }
            for (; j < j1; ++j) {
                int e0 = srt[j];
                float w0 = __expf(lrelu(s1[e0] + dd) - mb);
                float4 H0 = ldh4(h1, (size_t)e0 * 16 + 4 * q);
                accv.x += w0 * H0.x; accv.y += w0 * H0.y;
                accv.z += w0 * H0.z; accv.w += w0 * H0.w;
                den += w0;
            }
        }
        // stage accumulators to LDS (stride-17 rows)
        accs[gg * 17 + 4 * q + 0] = accv.x;
        accs[gg * 17 + 4 * q + 1] = accv.y;
        accs[gg * 17 + 4 * q + 2] = accv.z;
        accs[gg * 17 + 4 * q + 3] = accv.w;
        if (q == 0) accs[gg * 17 + 16] = den;
        __syncthreads();
    } else {
        // overflow: region incomplete -> full rescan of source edges (never-path)
        if (tid == 0) lofs_g[fb * LOFSTR + BNODES + 1] = 0;
        for (int i = tid; i < BNODES * 17; i += 512) accs[i] = 0.f;
        __syncthreads();
        if (tid < BNODES) {
            int n = node0 + tid;
            if (n < N) {
                float w = __expf(lrelu(s1[n] + dds[tid]) - mbs[tid]);
#pragma unroll
                for (int t = 0; t < 16; ++t)
                    accs[tid * 17 + t] = w * __half2float(h1[(size_t)n * 16 + t]);
                accs[tid * 17 + 16] = w;
            }
        }
        __syncthreads();
        for (int i = tid; i < E; i += 512) {
            int d = edst[i];
            if ((d >> FSH) != fb) continue;
            int nl = d & (BNODES - 1), src = esrc[i];
            float w = __expf(lrelu(s1[src] + dds[nl]) - mbs[nl]);
#pragma unroll
            for (int t = 0; t < 16; ++t)
                atomicAdd(&accs[nl * 17 + t], w * __half2float(h1[(size_t)src * 16 + t]));
            atomicAdd(&accs[nl * 17 + 16], w);
        }
        __syncthreads();
    }

    // epilogue: 32 groups of 16 lanes, 4 nodes each
    int g = tid >> 4, k = tid & 15;
    float sval = -3.4e38f;
#pragma unroll
    for (int qq = 0; qq < 4; ++qq) {
        int nl = g * 4 + qq, nn = node0 + nl;
        if (nn >= N) continue;           // group-uniform
        float inv = 1.f / accs[nl * 17 + 16];
        float o = fmaxf(accs[nl * 17 + k] * inv + sb[k], 0.f);
        float hh = 0.f;
#pragma unroll
        for (int kk = 0; kk < 16; ++kk) {
            float ov = __shfl(o, kk, 16);
            if (k < 10) hh += ov * sW[kk * 10 + k];
        }
        if (k >= 10) hh = 0.f;
        float ts = hh * sas[k];
        float td = hh * sad[k];
#pragma unroll
        for (int off = 1; off < 16; off <<= 1) {
            ts += __shfl_xor(ts, off, 16);
            td += __shfl_xor(td, off, 16);
        }
        h2[(size_t)nn * 16 + k] = __float2half_rn(hh);  // zero-padded cols 10..15
        if (k == 0) { s2[nn] = ts; d2[nn] = td; }
        sval = fmaxf(sval, ts);
    }
    float m = sval;
#pragma unroll
    for (int off = 32; off >= 1; off >>= 1) m = fmaxf(m, __shfl_xor(m, off));
    if ((tid & 63) == 0) wm[tid >> 6] = m;
    __syncthreads();
    if (tid == 0) {
        float bmx = wm[0];
#pragma unroll
        for (int i = 1; i < 8; ++i) bmx = fmaxf(bmx, wm[i]);
        atomicMax(gmax2, fenc(bmx));
    }
}

// ---- layer-2 agg: SORT-FREE (reads agg1's sorted region + lofs_g) ----
__global__ __launch_bounds__(512) void k_agg2(
    const unsigned* __restrict__ pairs,
    const int* __restrict__ esrc, const int* __restrict__ edst,
    const float* __restrict__ s2, const float* __restrict__ d2, const __half* __restrict__ h2,
    const float* __restrict__ b2, const float* __restrict__ Wl1, const float* __restrict__ bl1,
    const float* __restrict__ Wl2, const float* __restrict__ bl2,
    const unsigned* __restrict__ gmax2p, const int* __restrict__ lofs_g,
    float* __restrict__ out, int N, int E)
{
    __shared__ unsigned srt[CAPB];
    __shared__ float accs[BNODES * 17];
    __shared__ int lofs[BNODES + 1];
    __shared__ float dds[BNODES], mbs[BNODES];
    __shared__ float sW1[100], sb1[16], sW2[16], sb2g[16];
    __shared__ float sbl2;
    __shared__ int s_ok;

    int tid = threadIdx.x;
    int fb = blockIdx.x;
    if (tid < 100) sW1[tid] = Wl1[tid];
    if (tid < 16) {
        sb1[tid]  = (tid < 10) ? bl1[tid] : 0.f;
        sW2[tid]  = (tid < 10) ? Wl2[tid] : 0.f;
        sb2g[tid] = (tid < 10) ? b2[tid]  : 0.f;
    }
    if (tid == 0) sbl2 = bl2[0];
    if (tid <= BNODES) lofs[tid] = lofs_g[fb * LOFSTR + tid];
    if (tid == 256) s_ok = lofs_g[fb * LOFSTR + BNODES + 1];
    int node0 = fb << FSH;
    float g0 = fdec(*gmax2p);
    if (tid < BNODES) {
        int n = node0 + tid;
        float dd = (n < N) ? d2[n] : 0.f;
        dds[tid] = dd; mbs[tid] = lrelu(g0 + dd);
    }
    __syncthreads();

    int rbase = fb * CAPB;
    int gg = tid >> 2, q = tid & 3;

    if (s_ok) {
        // coalesced copy of the pre-sorted srcs into LDS (no atomics/scan)
        int cnt = lofs[BNODES];
#pragma unroll
        for (int u = 0; u < PES; ++u) {
            int i = tid + u * 512;
            if (i < cnt) srt[i] = pairs[rbase + i];
        }
        __syncthreads();

        int n = node0 + gg;
        float4 accv; float den;
        if (n < N) {
            float w = __expf(lrelu(s2[n] + dds[gg]) - mbs[gg]);
            float4 hv = ldh4(h2, (size_t)n * 16 + 4 * q);   // zero-padded
            accv = make_float4(w * hv.x, w * hv.y, w * hv.z, w * hv.w);
            den = w;
        } else { accv = make_float4(0.f, 0.f, 0.f, 0.f); den = 0.f; }
        {
            float dd = dds[gg], mb = mbs[gg];
            int j = lofs[gg], j1 = lofs[gg + 1];
            for (; j + 4 <= j1; j += 4) {
                int e0 = srt[j], e1 = srt[j + 1], e2 = srt[j + 2], e3 = srt[j + 3];
                float4 H0 = ldh4(h2, (size_t)e0 * 16 + 4 * q);
                float4 H1 = ldh4(h2, (size_t)e1 * 16 + 4 * q);
                float4 H2 = ldh4(h2, (size_t)e2 * 16 + 4 * q);
                float4 H3 = ldh4(h2, (size_t)e3 * 16 + 4 * q);
                int eq = srt[j + q];
                float wq = __expf(lrelu(s2[eq] + dd) - mb);
                float w0 = __shfl(wq, 0, 4), w1 = __shfl(wq, 1, 4);
                float w2 = __shfl(wq, 2, 4), w3 = __shfl(wq, 3, 4);
                accv.x += w0 * H0.x + w1 * H1.x + w2 * H2.x + w3 * H3.x;
                accv.y += w0 * H0.y + w1 * H1.y + w2 * H2.y + w3 * H3.y;
                accv.z += w0 * H0.z + w1 * H1.z + w2 * H2.z + w3 * H3.z;
                accv.w += w0 * H0.w + w1 * H1.w + w2 * H2.w + w3 * H3.w;
                den += (w0 + w1) + (w2 + w3);
            }
            for (; j < j1; ++j) {
                int e0 = srt[j];
                float w0 = __expf(lrelu(s2[e0] + dd) - mb);
                float4 H0 = ldh4(h2, (size_t)e0 * 16 + 4 * q);
                accv.x += w0 * H0.x; accv.y += w0 * H0.y;
                accv.z += w0 * H0.z; accv.w += w0 * H0.w;
                den += w0;
            }
        }
        accs[gg * 17 + 4 * q + 0] = accv.x;
        accs[gg * 17 + 4 * q + 1] = accv.y;
        accs[gg * 17 + 4 * q + 2] = accv.z;
        accs[gg * 17 + 4 * q + 3] = accv.w;
        if (q == 0) accs[gg * 17 + 16] = den;
        __syncthreads();
    } else {
        for (int i = tid; i < BNODES * 17; i += 512) accs[i] = 0.f;
        __syncthreads();
        if (tid < BNODES) {
            int n = node0 + tid;
            if (n < N) {
                float w = __expf(lrelu(s2[n] + dds[tid]) - mbs[tid]);
#pragma unroll
                for (int t = 0; t < 16; ++t)
                    accs[tid * 17 + t] = w * __half2float(h2[(size_t)n * 16 + t]);
                accs[tid * 17 + 16] = w;
            }
        }
        __syncthreads();
        for (int i = tid; i < E; i += 512) {
            int d = edst[i];
            if ((d >> FSH) != fb) continue;
            int nl = d & (BNODES - 1), src = esrc[i];
            float w = __expf(lrelu(s2[src] + dds[nl]) - mbs[nl]);
#pragma unroll
            for (int t = 0; t < 16; ++t)
                atomicAdd(&accs[nl * 17 + t], w * __half2float(h2[(size_t)src * 16 + t]));
            atomicAdd(&accs[nl * 17 + 16], w);
        }
        __syncthreads();
    }

    int g = tid >> 4, k = tid & 15;
    bool fk = k < 10;
#pragma unroll
    for (int qq = 0; qq < 4; ++qq) {
        int nl = g * 4 + qq, nn = node0 + nl;
        if (nn >= N) continue;           // group-uniform
        float inv = 1.f / accs[nl * 17 + 16];
        float o = fk ? accs[nl * 17 + k] * inv + sb2g[k] : 0.f;
        float v = sb1[k];
#pragma unroll
        for (int kk = 0; kk < 10; ++kk) {
            float ov = __shfl(o, kk, 16);
            if (fk) v += ov * sW1[kk * 10 + k];
        }
        float t = fmaxf(v, 0.f);
        float cc = t * sW2[k];           // zero for k>=10
#pragma unroll
        for (int off = 1; off < 16; off <<= 1) cc += __shfl_xor(cc, off, 16);
        if (k == 0) out[nn] = cc + sbl2;
    }
}

extern "C" void kernel_launch(void* const* d_in, const int* in_sizes, int n_in,
                              void* d_out, int out_size, void* d_ws, size_t ws_size,
                              hipStream_t stream)
{
    const float* x   = (const float*)d_in[0];
    const int*   ei  = (const int*)  d_in[1];   // [2][E] int32
    const float* W1  = (const float*)d_in[2];
    const float* a1s = (const float*)d_in[3];
    const float* a1d = (const float*)d_in[4];
    const float* b1  = (const float*)d_in[5];
    const float* W2  = (const float*)d_in[6];
    const float* a2s = (const float*)d_in[7];
    const float* a2d = (const float*)d_in[8];
    const float* b2  = (const float*)d_in[9];
    const float* Wl1 = (const float*)d_in[10];
    const float* bl1 = (const float*)d_in[11];
    const float* Wl2 = (const float*)d_in[12];
    const float* bl2 = (const float*)d_in[13];

    int N = in_sizes[0] / 128;
    int E = in_sizes[1] / 2;
    const int* ei_src = ei;
    const int* ei_dst = ei + E;
    int NSB = (N + BNODES - 1) >> FSH;       // 782 buckets (<= NSBMAX)

    size_t Np = ((size_t)N + 3) & ~(size_t)3;
    size_t need_bytes = (16 + (size_t)NSB * 16) * 4 + Np * 20 * 4
                      + (size_t)NSB * CAPB * 4 + (size_t)NSB * LOFSTR * 4;
    if (ws_size < need_bytes) return;  // degrade to wrong-answer, never fault

    // layout: [gmax1 gmax2 pad..16][bcur NSB*16][h1 s1 d1 h2 s2 d2][pairs][lofs_g]
    unsigned* gmax1 = (unsigned*)d_ws;       // [0]
    unsigned* gmax2 = gmax1 + 1;             // [1]
    int* bcur = (int*)d_ws + 16;             // NSB*16 (1 cursor per 64B), RELATIVE
    float* rest = (float*)d_ws + 16 + (size_t)NSB * 16;
    __half* h1 = (__half*)rest;              // Np*16 halves
    float* s1 = rest + Np * 8;               // Np
    float* d1 = s1 + Np;                     // Np
    __half* h2 = (__half*)(d1 + Np);         // Np*16 halves (cols 10..15 zero)
    float* s2 = (float*)(h2) + Np * 8;       // Np
    float* d2 = s2 + Np;                     // Np
    unsigned* pairs = (unsigned*)(d2 + Np);  // NSB*CAPB
    int* lofs_g = (int*)(pairs + (size_t)NSB * CAPB);  // NSB*LOFSTR

    int NG = (N + 63) / 64;
    int NC = (E + TILE - 1) / TILE;

    // zero gmax + relative bucket cursors in one memset (replaces k_init)
    hipMemsetAsync(d_ws, 0, (16 + (size_t)NSB * 16) * sizeof(int), stream);
    hipLaunchKernelGGL(k_front, dim3(NG + NC), dim3(256), 0, stream,
                       x, W1, a1s, a1d, h1, s1, d1, gmax1,
                       ei_src, ei_dst, bcur, pairs, N, E, NG, NC, NSB);
    hipLaunchKernelGGL(k_agg1, dim3(NSB), dim3(512), 0, stream,
                       bcur, pairs, ei_src, ei_dst, s1, d1, h1, b1, W2, a2s, a2d,
                       h2, s2, d2, gmax1, gmax2, lofs_g, N, E);
    hipLaunchKernelGGL(k_agg2, dim3(NSB), dim3(512), 0, stream,
                       pairs, ei_src, ei_dst, s2, d2, h2, b2, Wl1, bl1, Wl2, bl2,
                       gmax2, lofs_g, (float*)d_out, N, E);
}

// Round 9
// 258.785 us; speedup vs baseline: 1.0422x; 1.0422x over previous
//
#include <hip/hip_runtime.h>
#include <hip/hip_fp16.h>

// GAT (2 layers, heads=1) + 2-layer MLP head. N=100000, E=3200000, D=128.
// R24 = R22 aggs (best measured) + 512-thread front. k_front was
// latency-bound (VALU 10%, HBM 14%, occ 30%): 256-thr blocks capped the CU
// at 16-20 resident waves. 512-thr blocks (csplit TILE 4096 w/ EPT=8 +
// rid[] flush; gemm 128 nodes/block) hit the full 32-wave/CU cap at
// 4 blocks/CU. R23's rid-byte-packing flush reverted (3 extra dependent
// LDS reads/edge cost more than the LDS it saved).
// agg1 sort + sorted write-back, agg2 sort-free (R22, proven).
// Overflow -> full-rescan fallback keeps arbitrary inputs correct.
// Softmax stabilization uses a GLOBAL upper bound m̄_i = leaky(gmax_asrc+adst_i)
// (valid since leaky_relu is monotone); alpha is mathematically unchanged.

#define NEG 0.2f
#define FSH 7
#define BNODES 128           // nodes per bucket
#define NSBMAX 1024          // >= ceil(100000/128)=782
#define CAPB 4608            // per-bucket region capacity (mean 4096, +8 sigma)
#define TILE 4096            // edges per csplit block (512 threads, 8/thread)
#define EPT 8                // TILE/512 register-staged edges per thread
#define PES 9                // ceil(CAPB/512) register-staged pairs per thread
#define LOFSTR 132           // lofs_g stride per bucket (129 lofs + flag + pad)

__device__ __forceinline__ float lrelu(float x) { return x > 0.0f ? x : NEG * x; }

__device__ __forceinline__ unsigned fenc(float f) {
    unsigned u = __float_as_uint(f);
    return (u & 0x80000000u) ? ~u : (u | 0x80000000u);
}
__device__ __forceinline__ float fdec(unsigned e) {
    return (e & 0x80000000u) ? __uint_as_float(e & 0x7FFFFFFFu) : __uint_as_float(~e);
}

// load 4 consecutive halves as float4 (8B load)
__device__ __forceinline__ float4 ldh4(const __half* h, size_t off) {
    uint2 u = *(const uint2*)(h + off);
    __half2 a = *(__half2*)&u.x, b = *(__half2*)&u.y;
    float2 fa = __half22float2(a), fb = __half22float2(b);
    return make_float4(fa.x, fa.y, fb.x, fb.y);
}

// ---- fused front-end: gemm role + csplit role in one 512-thread grid ----
__global__ __launch_bounds__(512) void k_front(
    const float* __restrict__ x, const float* __restrict__ W1,
    const float* __restrict__ a1s, const float* __restrict__ a1d,
    __half* __restrict__ h1, float* __restrict__ s1, float* __restrict__ d1,
    unsigned* __restrict__ gmax,
    const int* __restrict__ esrc, const int* __restrict__ edst,
    int* __restrict__ bcur, unsigned* __restrict__ pairs,
    int N, int E, int NG, int NC, int NSB)
{
    // union LDS: csplit lsrt 4096 + hist/ofs/base 3*1024 + wsum 8 + rid 2048
    //            = 9224 words (36.9KB) -> 4 blocks/CU = 32 waves (full cap)
    //            gemm: padded W 2060 + wm 8 (8.3KB)
    __shared__ float smem[9224];
    int tid = threadIdx.x;
    int bid = blockIdx.x;
    long long T = (long long)NG + NC;
    int before = (int)(((long long)bid * NC) / T);       // csplit blocks before bid
    int isc = (int)((((long long)bid + 1) * NC) / T) > before;

    if (isc) {
        // ------------------ csplit role ------------------
        unsigned* lsrt = (unsigned*)smem;                   // 4096
        int* lhist = (int*)smem + TILE;                     // 1024
        int* lofs  = lhist + NSBMAX;                        // 1024
        int* gbase = lofs + NSBMAX;                         // 1024
        int* wsum  = gbase + NSBMAX;                        // 8
        unsigned short* rid = (unsigned short*)(smem + TILE + 3 * NSBMAX + 8); // 4096 ushorts
        int cid = before;
        int base = cid * TILE;
        int tcnt = min(TILE, E - base);
        for (int i = tid; i < NSB; i += 512) lhist[i] = 0;
        __syncthreads();
        // hist pass with register-staged dst
        int ed[EPT];
#pragma unroll
        for (int u = 0; u < EPT; ++u) {
            int i = tid + u * 512;
            ed[u] = (i < tcnt) ? edst[base + i] : -1;
            if (ed[u] >= 0) atomicAdd(&lhist[ed[u] >> FSH], 1);
        }
        __syncthreads();
        // 2 keys per thread scan (NSB <= 1024 = 2*512)
        int i0 = 2 * tid;
        int a = (i0 < NSB) ? lhist[i0] : 0;
        int b = (i0 + 1 < NSB) ? lhist[i0 + 1] : 0;
        int s = a + b, pfx = s;
#pragma unroll
        for (int off = 1; off < 64; off <<= 1) {
            int t = __shfl_up(pfx, off, 64);
            if ((tid & 63) >= off) pfx += t;
        }
        if ((tid & 63) == 63) wsum[tid >> 6] = pfx;
        __syncthreads();
        int carry = 0;
        for (int w = 0; w < (tid >> 6); ++w) carry += wsum[w];
        int excl = pfx + carry - s;
        if (i0 < NSB) {
            lofs[i0] = excl;
            gbase[i0] = a ? atomicAdd(&bcur[i0 * 16], a) : 0;
        }
        if (i0 + 1 < NSB) {
            lofs[i0 + 1] = excl + a;
            gbase[i0 + 1] = b ? atomicAdd(&bcur[(i0 + 1) * 16], b) : 0;
        }
        __syncthreads();
        if (i0 < NSB) lhist[i0] = lofs[i0];        // cursors
        if (i0 + 1 < NSB) lhist[i0 + 1] = lofs[i0 + 1];
        __syncthreads();
        // scatter pass: LDS sort + record run id (no flush binary search)
#pragma unroll
        for (int u = 0; u < EPT; ++u) {
            int i = tid + u * 512;
            if (ed[u] >= 0) {
                int d = ed[u], srcv = esrc[base + i];
                int bb = d >> FSH;
                int pos = atomicAdd(&lhist[bb], 1);
                lsrt[pos] = ((unsigned)(d & (BNODES - 1)) << 17) | (unsigned)srcv;
                rid[pos] = (unsigned short)bb;
            }
        }
        __syncthreads();
        // flush: independent iterations, coalesced run-contiguous stores
#pragma unroll
        for (int u = 0; u < EPT; ++u) {
            int i = tid + u * 512;
            if (i < tcnt) {
                int r = rid[i];
                int rel = gbase[r] + (i - lofs[r]);
                if (rel < CAPB) pairs[(size_t)r * CAPB + rel] = lsrt[i];
            }
        }
        return;
    }

    // ------------------ gemm role (128 nodes/block; j-partitioned lanes) ------------------
    float* sW = smem;                 // padded: idx i -> i + ((i>>9)<<2), max 2059
    float* wm = smem + 2060;          // 8
    int gid = bid - before;
    for (int i = tid; i < 2048; i += 512) sW[i + ((i >> 9) << 2)] = W1[i];
    int node0 = gid * 128;
    int node = node0 + (tid >> 2);
    int q = tid & 3;
    bool valid = node < N;
    // lane q owns j = q*32 .. q*32+31  (8 float4 of the node's x row)
    float4 xr[8];
    {
        const float4* xp = (const float4*)x + (size_t)node * 32 + q * 8;
#pragma unroll
        for (int k = 0; k < 8; ++k)
            xr[k] = valid ? xp[k] : make_float4(0.f, 0.f, 0.f, 0.f);
    }
    __syncthreads();

    float acc[16];
#pragma unroll
    for (int c = 0; c < 16; ++c) acc[c] = 0.f;
    int wbase = q * 516;             // q*32*16 + q*4 pad -> banks 4q.. (conflict-free)
#pragma unroll
    for (int k = 0; k < 8; ++k) {
        float xs0 = xr[k].x, xs1 = xr[k].y, xs2 = xr[k].z, xs3 = xr[k].w;
#pragma unroll
        for (int t = 0; t < 4; ++t) {
            float xv = (t == 0) ? xs0 : (t == 1) ? xs1 : (t == 2) ? xs2 : xs3;
            const float4* wrow = (const float4*)&sW[wbase + (k * 4 + t) * 16];
            float4 w0 = wrow[0], w1 = wrow[1], w2 = wrow[2], w3 = wrow[3];
            acc[0]  += xv * w0.x; acc[1]  += xv * w0.y; acc[2]  += xv * w0.z; acc[3]  += xv * w0.w;
            acc[4]  += xv * w1.x; acc[5]  += xv * w1.y; acc[6]  += xv * w1.z; acc[7]  += xv * w1.w;
            acc[8]  += xv * w2.x; acc[9]  += xv * w2.y; acc[10] += xv * w2.z; acc[11] += xv * w2.w;
            acc[12] += xv * w3.x; acc[13] += xv * w3.y; acc[14] += xv * w3.z; acc[15] += xv * w3.w;
        }
    }
    // butterfly over the 4 lanes: all lanes end with the full 16 sums
#pragma unroll
    for (int c = 0; c < 16; ++c) {
        acc[c] += __shfl_xor(acc[c], 1);
        acc[c] += __shfl_xor(acc[c], 2);
    }
    float sv = 0.f, dv = 0.f;
    {
        const float4* asp = (const float4*)a1s;
        const float4* adp = (const float4*)a1d;
#pragma unroll
        for (int r = 0; r < 4; ++r) {
            float4 as = asp[r], ad = adp[r];
            sv += acc[r*4+0]*as.x + acc[r*4+1]*as.y + acc[r*4+2]*as.z + acc[r*4+3]*as.w;
            dv += acc[r*4+0]*ad.x + acc[r*4+1]*ad.y + acc[r*4+2]*ad.z + acc[r*4+3]*ad.w;
        }
    }
    if (valid) {
        float4 av;
        if      (q == 0) av = make_float4(acc[0],  acc[1],  acc[2],  acc[3]);
        else if (q == 1) av = make_float4(acc[4],  acc[5],  acc[6],  acc[7]);
        else if (q == 2) av = make_float4(acc[8],  acc[9],  acc[10], acc[11]);
        else             av = make_float4(acc[12], acc[13], acc[14], acc[15]);
        __half2 p0 = __floats2half2_rn(av.x, av.y);
        __half2 p1 = __floats2half2_rn(av.z, av.w);
        uint2 u; u.x = *(unsigned*)&p0; u.y = *(unsigned*)&p1;
        *(uint2*)&h1[(size_t)node * 16 + q * 4] = u;
        if (q == 0) { s1[node] = sv; d1[node] = dv; }
    }
    float m = valid ? sv : -3.4e38f;
#pragma unroll
    for (int off = 32; off >= 1; off >>= 1) m = fmaxf(m, __shfl_xor(m, off));
    if ((tid & 63) == 0) wm[tid >> 6] = m;
    __syncthreads();
    if (tid == 0) {
        float bmx = wm[0];
#pragma unroll
        for (int i = 1; i < 8; ++i) bmx = fmaxf(bmx, wm[i]);
        atomicMax(gmax, fenc(bmx));
    }
}

// ---- layer-1 agg: R11 full-bucket sort+gather, plus sorted write-back ----
__global__ __launch_bounds__(512) void k_agg1(
    const int* __restrict__ bcur, unsigned* __restrict__ pairs,
    const int* __restrict__ esrc, const int* __restrict__ edst,
    const float* __restrict__ s1, const float* __restrict__ d1, const __half* __restrict__ h1,
    const float* __restrict__ b1, const float* __restrict__ W2,
    const float* __restrict__ a2s, const float* __restrict__ a2d,
    __half* __restrict__ h2, float* __restrict__ s2, float* __restrict__ d2,
    const unsigned* __restrict__ gmax1p, unsigned* __restrict__ gmax2,
    int* __restrict__ lofs_g, int N, int E)
{
    __shared__ unsigned srt[CAPB];
    __shared__ float accs[BNODES * 17];
    __shared__ int lcnt[BNODES];
    __shared__ int lofs[BNODES + 1];
    __shared__ float dds[BNODES], mbs[BNODES];
    __shared__ float sW[160], sb[16], sas[16], sad[16];
    __shared__ int wsum[8];
    __shared__ float wm[8];

    int tid = threadIdx.x;
    int fb = blockIdx.x;
    if (tid < 160) sW[tid] = W2[tid];
    if (tid < 16) {
        sb[tid]  = b1[tid];
        sas[tid] = (tid < 10) ? a2s[tid] : 0.f;
        sad[tid] = (tid < 10) ? a2d[tid] : 0.f;
    }
    int node0 = fb << FSH;
    float g0 = fdec(*gmax1p);
    if (tid < BNODES) {
        int n = node0 + tid;
        float dd = (n < N) ? d1[n] : 0.f;
        dds[tid] = dd; mbs[tid] = lrelu(g0 + dd);
        lcnt[tid] = 0;
    }
    __syncthreads();

    int rbase = fb * CAPB;
    int cnt = bcur[fb * 16];             // RELATIVE count; > CAPB means overflow
    int gg = tid >> 2, q = tid & 3;      // 128 groups x 4 lanes, 1 node each

    if (cnt <= CAPB) {
        // count pass with register staging (single global read of pairs)
        unsigned pe[PES];
#pragma unroll
        for (int u = 0; u < PES; ++u) {
            int i = tid + u * 512;
            bool ok = (i < cnt);
            pe[u] = ok ? pairs[rbase + i] : 0u;
            if (ok) atomicAdd(&lcnt[(pe[u] >> 17) & (BNODES - 1)], 1);
        }
        __syncthreads();
        // 128-key scan (padded to 512 threads)
        int c = (tid < BNODES) ? lcnt[tid] : 0;
        int pfx = c;
#pragma unroll
        for (int off = 1; off < 64; off <<= 1) {
            int t = __shfl_up(pfx, off, 64);
            if ((tid & 63) >= off) pfx += t;
        }
        if ((tid & 63) == 63) wsum[tid >> 6] = pfx;
        __syncthreads();
        int carry = 0;
        for (int w = 0; w < (tid >> 6); ++w) carry += wsum[w];
        pfx += carry;
        if (tid < BNODES) { lofs[tid + 1] = pfx; lcnt[tid] = pfx - c; }
        if (tid == 0) lofs[0] = 0;
        __syncthreads();
        // scatter pass from registers -> dst-sorted srcs
#pragma unroll
        for (int u = 0; u < PES; ++u) {
            int i = tid + u * 512;
            if (i < cnt) {
                unsigned p = pe[u];
                int pos = atomicAdd(&lcnt[(p >> 17) & (BNODES - 1)], 1);
                srt[pos] = p & 0x1FFFF;
            }
        }
        __syncthreads();

        // write-back sorted srcs over own region + lofs for the sort-free agg2
#pragma unroll
        for (int u = 0; u < PES; ++u) {
            int i = tid + u * 512;
            if (i < cnt) pairs[rbase + i] = srt[i];
        }
        if (tid <= BNODES) lofs_g[fb * LOFSTR + tid] = lofs[tid];
        if (tid == 0) lofs_g[fb * LOFSTR + BNODES + 1] = 1;

        // self-loop init + register gather (1 exp/edge via width-4 shfl)
        int n = node0 + gg;
        float4 accv; float den;
        if (n < N) {
            float w = __expf(lrelu(s1[n] + dds[gg]) - mbs[gg]);
            float4 hv = ldh4(h1, (size_t)n * 16 + 4 * q);
            accv = make_float4(w * hv.x, w * hv.y, w * hv.z, w * hv.w);
            den = w;
        } else { accv = make_float4(0.f, 0.f, 0.f, 0.f); den = 0.f; }
        {
            float dd = dds[gg], mb = mbs[gg];
            int j = lofs[gg], j1 = lofs[gg + 1];
            for (; j + 4 <= j1; j += 4) {
                int e0 = srt[j], e1 = srt[j + 1], e2 = srt[j + 2], e3 = srt[j + 3];
                float4 H0 = ldh4(h1, (size_t)e0 * 16 + 4 * q);
                float4 H1 = ldh4(h1, (size_t)e1 * 16 + 4 * q);
                float4 H2 = ldh4(h1, (size_t)e2 * 16 + 4 * q);
                float4 H3 = ldh4(h1, (size_t)e3 * 16 + 4 * q);
                int eq = srt[j + q];
                float wq = __expf(lrelu(s1[eq] + dd) - mb);
                float w0 = __shfl(wq, 0, 4), w1 = __shfl(wq, 1, 4);
                float w2 = __shfl(wq, 2, 4), w3 = __shfl(wq, 3, 4);
                accv.x += w0 * H0.x + w1 * H1.x + w2 * H2.x + w3 * H3.x;
                accv.y += w0 * H0.y + w1 * H1.y + w2 * H2.y + w3 * H3.y;
                accv.z += w0 * H0.z + w1 * H1.z + w2 * H2.z + w3 * H3.z;
                accv.w += w0 * H0.w + w1 * H1.w + w2 * H2.w + w3 * H3.w;
                den += (w0 + w1) + (w2 + w3);
            }
            for (; j < j1; ++j) {
                int e0 = srt[j];
                float w0 = __expf(lrelu(s1[e0] + dd) - mb);
                float4 H0 = ldh4(h1, (size_t)e0 * 16 + 4 * q);
                accv.x += w0 * H0.x; accv.y += w0 * H0.y;
                accv.z += w0 * H0.z; accv.w += w0 * H0.w;
                den += w0;
            }
        }
        // stage accumulators to LDS (stride-17 rows)
        accs[gg * 17 + 4 * q + 0] = accv.x;
        accs[gg * 17 + 4 * q + 1] = accv.y;
        accs[gg * 17 + 4 * q + 2] = accv.z;
        accs[gg * 17 + 4 * q + 3] = accv.w;
        if (q == 0) accs[gg * 17 + 16] = den;
        __syncthreads();
    } else {
        // overflow: region incomplete -> full rescan of source edges (never-path)
        if (tid == 0) lofs_g[fb * LOFSTR + BNODES + 1] = 0;
        for (int i = tid; i < BNODES * 17; i += 512) accs[i] = 0.f;
        __syncthreads();
        if (tid < BNODES) {
            int n = node0 + tid;
            if (n < N) {
                float w = __expf(lrelu(s1[n] + dds[tid]) - mbs[tid]);
#pragma unroll
                for (int t = 0; t < 16; ++t)
                    accs[tid * 17 + t] = w * __half2float(h1[(size_t)n * 16 + t]);
                accs[tid * 17 + 16] = w;
            }
        }
        __syncthreads();
        for (int i = tid; i < E; i += 512) {
            int d = edst[i];
            if ((d >> FSH) != fb) continue;
            int nl = d & (BNODES - 1), src = esrc[i];
            float w = __expf(lrelu(s1[src] + dds[nl]) - mbs[nl]);
#pragma unroll
            for (int t = 0; t < 16; ++t)
                atomicAdd(&accs[nl * 17 + t], w * __half2float(h1[(size_t)src * 16 + t]));
            atomicAdd(&accs[nl * 17 + 16], w);
        }
        __syncthreads();
    }

    // epilogue: 32 groups of 16 lanes, 4 nodes each
    int g = tid >> 4, k = tid & 15;
    float sval = -3.4e38f;
#pragma unroll
    for (int qq = 0; qq < 4; ++qq) {
        int nl = g * 4 + qq, nn = node0 + nl;
        if (nn >= N) continue;           // group-uniform
        float inv = 1.f / accs[nl * 17 + 16];
        float o = fmaxf(accs[nl * 17 + k] * inv + sb[k], 0.f);
        float hh = 0.f;
#pragma unroll
        for (int kk = 0; kk < 16; ++kk) {
            float ov = __shfl(o, kk, 16);
            if (k < 10) hh += ov * sW[kk * 10 + k];
        }
        if (k >= 10) hh = 0.f;
        float ts = hh * sas[k];
        float td = hh * sad[k];
#pragma unroll
        for (int off = 1; off < 16; off <<= 1) {
            ts += __shfl_xor(ts, off, 16);
            td += __shfl_xor(td, off, 16);
        }
        h2[(size_t)nn * 16 + k] = __float2half_rn(hh);  // zero-padded cols 10..15
        if (k == 0) { s2[nn] = ts; d2[nn] = td; }
        sval = fmaxf(sval, ts);
    }
    float m = sval;
#pragma unroll
    for (int off = 32; off >= 1; off >>= 1) m = fmaxf(m, __shfl_xor(m, off));
    if ((tid & 63) == 0) wm[tid >> 6] = m;
    __syncthreads();
    if (tid == 0) {
        float bmx = wm[0];
#pragma unroll
        for (int i = 1; i < 8; ++i) bmx = fmaxf(bmx, wm[i]);
        atomicMax(gmax2, fenc(bmx));
    }
}

// ---- layer-2 agg: SORT-FREE (reads agg1's sorted region + lofs_g) ----
__global__ __launch_bounds__(512) void k_agg2(
    const unsigned* __restrict__ pairs,
    const int* __restrict__ esrc, const int* __restrict__ edst,
    const float* __restrict__ s2, const float* __restrict__ d2, const __half* __restrict__ h2,
    const float* __restrict__ b2, const float* __restrict__ Wl1, const float* __restrict__ bl1,
    const float* __restrict__ Wl2, const float* __restrict__ bl2,
    const unsigned* __restrict__ gmax2p, const int* __restrict__ lofs_g,
    float* __restrict__ out, int N, int E)
{
    __shared__ unsigned srt[CAPB];
    __shared__ float accs[BNODES * 17];
    __shared__ int lofs[BNODES + 1];
    __shared__ float dds[BNODES], mbs[BNODES];
    __shared__ float sW1[100], sb1[16], sW2[16], sb2g[16];
    __shared__ float sbl2;
    __shared__ int s_ok;

    int tid = threadIdx.x;
    int fb = blockIdx.x;
    if (tid < 100) sW1[tid] = Wl1[tid];
    if (tid < 16) {
        sb1[tid]  = (tid < 10) ? bl1[tid] : 0.f;
        sW2[tid]  = (tid < 10) ? Wl2[tid] : 0.f;
        sb2g[tid] = (tid < 10) ? b2[tid]  : 0.f;
    }
    if (tid == 0) sbl2 = bl2[0];
    if (tid <= BNODES) lofs[tid] = lofs_g[fb * LOFSTR + tid];
    if (tid == 256) s_ok = lofs_g[fb * LOFSTR + BNODES + 1];
    int node0 = fb << FSH;
    float g0 = fdec(*gmax2p);
    if (tid < BNODES) {
        int n = node0 + tid;
        float dd = (n < N) ? d2[n] : 0.f;
        dds[tid] = dd; mbs[tid] = lrelu(g0 + dd);
    }
    __syncthreads();

    int rbase = fb * CAPB;
    int gg = tid >> 2, q = tid & 3;

    if (s_ok) {
        // coalesced copy of the pre-sorted srcs into LDS (no atomics/scan)
        int cnt = lofs[BNODES];
#pragma unroll
        for (int u = 0; u < PES; ++u) {
            int i = tid + u * 512;
            if (i < cnt) srt[i] = pairs[rbase + i];
        }
        __syncthreads();

        int n = node0 + gg;
        float4 accv; float den;
        if (n < N) {
            float w = __expf(lrelu(s2[n] + dds[gg]) - mbs[gg]);
            float4 hv = ldh4(h2, (size_t)n * 16 + 4 * q);   // zero-padded
            accv = make_float4(w * hv.x, w * hv.y, w * hv.z, w * hv.w);
            den = w;
        } else { accv = make_float4(0.f, 0.f, 0.f, 0.f); den = 0.f; }
        {
            float dd = dds[gg], mb = mbs[gg];
            int j = lofs[gg], j1 = lofs[gg + 1];
            for (; j + 4 <= j1; j += 4) {
                int e0 = srt[j], e1 = srt[j + 1], e2 = srt[j + 2], e3 = srt[j + 3];
                float4 H0 = ldh4(h2, (size_t)e0 * 16 + 4 * q);
                float4 H1 = ldh4(h2, (size_t)e1 * 16 + 4 * q);
                float4 H2 = ldh4(h2, (size_t)e2 * 16 + 4 * q);
                float4 H3 = ldh4(h2, (size_t)e3 * 16 + 4 * q);
                int eq = srt[j + q];
                float wq = __expf(lrelu(s2[eq] + dd) - mb);
                float w0 = __shfl(wq, 0, 4), w1 = __shfl(wq, 1, 4);
                float w2 = __shfl(wq, 2, 4), w3 = __shfl(wq, 3, 4);
                accv.x += w0 * H0.x + w1 * H1.x + w2 * H2.x + w3 * H3.x;
                accv.y += w0 * H0.y + w1 * H1.y + w2 * H2.y + w3 * H3.y;
                accv.z += w0 * H0.z + w1 * H1.z + w2 * H2.z + w3 * H3.z;
                accv.w += w0 * H0.w + w1 * H1.w + w2 * H2.w + w3 * H3.w;
                den += (w0 + w1) + (w2 + w3);
            }
            for (; j < j1; ++j) {
                int e0 = srt[j];
                float w0 = __expf(lrelu(s2[e0] + dd) - mb);
                float4 H0 = ldh4(h2, (size_t)e0 * 16 + 4 * q);
                accv.x += w0 * H0.x; accv.y += w0 * H0.y;
                accv.z += w0 * H0.z; accv.w += w0 * H0.w;
                den += w0;
            }
        }
        accs[gg * 17 + 4 * q + 0] = accv.x;
        accs[gg * 17 + 4 * q + 1] = accv.y;
        accs[gg * 17 + 4 * q + 2] = accv.z;
        accs[gg * 17 + 4 * q + 3] = accv.w;
        if (q == 0) accs[gg * 17 + 16] = den;
        __syncthreads();
    } else {
        for (int i = tid; i < BNODES * 17; i += 512) accs[i] = 0.f;
        __syncthreads();
        if (tid < BNODES) {
            int n = node0 + tid;
            if (n < N) {
                float w = __expf(lrelu(s2[n] + dds[tid]) - mbs[tid]);
#pragma unroll
                for (int t = 0; t < 16; ++t)
                    accs[tid * 17 + t] = w * __half2float(h2[(size_t)n * 16 + t]);
                accs[tid * 17 + 16] = w;
            }
        }
        __syncthreads();
        for (int i = tid; i < E; i += 512) {
            int d = edst[i];
            if ((d >> FSH) != fb) continue;
            int nl = d & (BNODES - 1), src = esrc[i];
            float w = __expf(lrelu(s2[src] + dds[nl]) - mbs[nl]);
#pragma unroll
            for (int t = 0; t < 16; ++t)
                atomicAdd(&accs[nl * 17 + t], w * __half2float(h2[(size_t)src * 16 + t]));
            atomicAdd(&accs[nl * 17 + 16], w);
        }
        __syncthreads();
    }

    int g = tid >> 4, k = tid & 15;
    bool fk = k < 10;
#pragma unroll
    for (int qq = 0; qq < 4; ++qq) {
        int nl = g * 4 + qq, nn = node0 + nl;
        if (nn >= N) continue;           // group-uniform
        float inv = 1.f / accs[nl * 17 + 16];
        float o = fk ? accs[nl * 17 + k] * inv + sb2g[k] : 0.f;
        float v = sb1[k];
#pragma unroll
        for (int kk = 0; kk < 10; ++kk) {
            float ov = __shfl(o, kk, 16);
            if (fk) v += ov * sW1[kk * 10 + k];
        }
        float t = fmaxf(v, 0.f);
        float cc = t * sW2[k];           // zero for k>=10
#pragma unroll
        for (int off = 1; off < 16; off <<= 1) cc += __shfl_xor(cc, off, 16);
        if (k == 0) out[nn] = cc + sbl2;
    }
}

extern "C" void kernel_launch(void* const* d_in, const int* in_sizes, int n_in,
                              void* d_out, int out_size, void* d_ws, size_t ws_size,
                              hipStream_t stream)
{
    const float* x   = (const float*)d_in[0];
    const int*   ei  = (const int*)  d_in[1];   // [2][E] int32
    const float* W1  = (const float*)d_in[2];
    const float* a1s = (const float*)d_in[3];
    const float* a1d = (const float*)d_in[4];
    const float* b1  = (const float*)d_in[5];
    const float* W2  = (const float*)d_in[6];
    const float* a2s = (const float*)d_in[7];
    const float* a2d = (const float*)d_in[8];
    const float* b2  = (const float*)d_in[9];
    const float* Wl1 = (const float*)d_in[10];
    const float* bl1 = (const float*)d_in[11];
    const float* Wl2 = (const float*)d_in[12];
    const float* bl2 = (const float*)d_in[13];

    int N = in_sizes[0] / 128;
    int E = in_sizes[1] / 2;
    const int* ei_src = ei;
    const int* ei_dst = ei + E;
    int NSB = (N + BNODES - 1) >> FSH;       // 782 buckets (<= NSBMAX)

    size_t Np = ((size_t)N + 3) & ~(size_t)3;
    size_t need_bytes = (16 + (size_t)NSB * 16) * 4 + Np * 20 * 4
                      + (size_t)NSB * CAPB * 4 + (size_t)NSB * LOFSTR * 4;
    if (ws_size < need_bytes) return;  // degrade to wrong-answer, never fault

    // layout: [gmax1 gmax2 pad..16][bcur NSB*16][h1 s1 d1 h2 s2 d2][pairs][lofs_g]
    unsigned* gmax1 = (unsigned*)d_ws;       // [0]
    unsigned* gmax2 = gmax1 + 1;             // [1]
    int* bcur = (int*)d_ws + 16;             // NSB*16 (1 cursor per 64B), RELATIVE
    float* rest = (float*)d_ws + 16 + (size_t)NSB * 16;
    __half* h1 = (__half*)rest;              // Np*16 halves
    float* s1 = rest + Np * 8;               // Np
    float* d1 = s1 + Np;                     // Np
    __half* h2 = (__half*)(d1 + Np);         // Np*16 halves (cols 10..15 zero)
    float* s2 = (float*)(h2) + Np * 8;       // Np
    float* d2 = s2 + Np;                     // Np
    unsigned* pairs = (unsigned*)(d2 + Np);  // NSB*CAPB
    int* lofs_g = (int*)(pairs + (size_t)NSB * CAPB);  // NSB*LOFSTR

    int NG = (N + 127) / 128;
    int NC = (E + TILE - 1) / TILE;

    // zero gmax + relative bucket cursors in one memset (replaces k_init)
    hipMemsetAsync(d_ws, 0, (16 + (size_t)NSB * 16) * sizeof(int), stream);
    hipLaunchKernelGGL(k_front, dim3(NG + NC), dim3(512), 0, stream,
                       x, W1, a1s, a1d, h1, s1, d1, gmax1,
                       ei_src, ei_dst, bcur, pairs, N, E, NG, NC, NSB);
    hipLaunchKernelGGL(k_agg1, dim3(NSB), dim3(512), 0, stream,
                       bcur, pairs, ei_src, ei_dst, s1, d1, h1, b1, W2, a2s, a2d,
                       h2, s2, d2, gmax1, gmax2, lofs_g, N, E);
    hipLaunchKernelGGL(k_agg2, dim3(NSB), dim3(512), 0, stream,
                       pairs, ei_src, ei_dst, s2, d2, h2, b2, Wl1, bl1, Wl2, bl2,
                       gmax2, lofs_g, (float*)d_out, N, E);
}